// Round 24
// baseline (344.113 us; speedup 1.0000x reference)
//
#include <hip/hip_runtime.h>

// Soft-DTW (gamma=1), batched 64 x (1024 vs 1024, 2-D points).
//
// === R24: R23 + two bit-exact chain-op deletions ===
//  1. nbh1 = up + vr[k] replaces the 64-bit (lane==0 ? vr[k] : up) select.
//     Exact: wave_shr:1 with old=0 gives lane 0 up==0.0; vr[] is written
//     only on lane 0 (0-init, never touched elsewhere) so lanes>=1 have
//     vr[k]==0.0. One addend is always +0.0, all values >=0 -> x+0.0==x.
//     Saves 2 cndmasks/step, costs 1 v_add_f64.
//  2. k2l/k2h stored as f64: deletes the 32/epoch v_cvt_f64_f32 from the
//     chain region (widening is exact either way -> identical values).
// R23's lgkm-only barrier was NULL (288.1 ~ 287.4) -> load drain was not
// the stall; kept anyway (harmless). R22's wins kept: wave_shr:1 neighbor
// pass, snapshot only on wave 7.
//
// Champion structure (R15-R17, 287.4us): one block per batch, 64 blocks x
// 512 thr, 8 waves (2 waves/SIMD), lane owns rows 2l (lo) / 2l+1 (hi); hi
// cell's predecessors are the lane's own cur_lo/old_lo (no DPP); lo+hi
// independent per step (2x ILP); contour reuse c_h(k) = c_l(k-1); LDS
// parity ring between waves; K=16 diagonals/epoch, one barrier per epoch.
// Closed axes (measured losses): cross-block CU-spread (R10/11/13/14/18),
// K=8/32 (R8/R14/R20), producer-asm pins (R19), vmcnt barrier drain (R23),
// >2 waves/SIMD (structurally impossible at 64 batches x 8 waves).
//
// Core (verified absmax 0.0 since R8): exp2-domain Z = 2^(off - R*log2e);
//   Z_d[i] = 2^(-D*log2e) * (Zdiag + Zup + Zleft)
// Per-cell op order bit-identical: zn = k2 * ((nb2 + nb1) + cur); zero
// transcendentals on-chain; per-wave exact power-of-2 rescale per epoch
// (DPP max-reduce, pure VALU); lane-0 neighbor values converted by exact
// 2^(off-oin) two-stage factors; ring parity double-buffer (reader epoch g
// reads writer epoch g-1, parity (g^1)&1; overwrite 2 barriers later).
// Inactive cells: k2=0 -> zn=0. Final cell (row 1023, d=2046) snapshotted
// at its own step (exact); R = (res_off - log2(res)) * ln2.

#define N 1024
#define TPB 512
#define WPB 8                                  // waves per block = per batch
#define K 16                                   // diagonals per epoch
#define NGRP ((128 * (WPB - 1) + 1148) / K + (WPB - 1) + 1)   // 135
#define L2E 1.442695040888963f
#define LN2D 0.6931471805599453

#define PIN_D(x) asm volatile("" :: "v"(x))

// Epoch barrier: order LDS (ring) only; global k2 loads stay in flight.
#define EPOCH_BARRIER() \
    asm volatile("s_waitcnt lgkmcnt(0)\n\ts_barrier" ::: "memory")

__device__ __forceinline__ float sqdist2(float2 a, float2 b) {
    float dx = a.x - b.x;
    float dy = a.y - b.y;
    return dx * dx + dy * dy;
}

// 64-bit DPP move (two 32-bit halves, same lane pattern; invalid lanes -> 0).
template <int CTRL>
__device__ __forceinline__ double dpp_movd(double src) {
    long long s = __double_as_longlong(src);
    int lo = __builtin_amdgcn_update_dpp(0, (int)(s & 0xffffffffLL),
                                         CTRL, 0xF, 0xF, false);
    int hi = __builtin_amdgcn_update_dpp(0, (int)(s >> 32),
                                         CTRL, 0xF, 0xF, false);
    return __longlong_as_double(((long long)hi << 32) | (unsigned int)lo);
}

template <int CTRL>
__device__ __forceinline__ int dpp_maxstep(int x) {
    int s = __builtin_amdgcn_update_dpp(0, x, CTRL, 0xF, 0xF, false);
    return max(x, s);
}

// Full 64-lane max of a nonneg int, pure VALU (no LDS); result wave-uniform.
__device__ __forceinline__ int wave_max_i(int x) {
    x = dpp_maxstep<0x111>(x);   // row_shr:1
    x = dpp_maxstep<0x112>(x);   // row_shr:2
    x = dpp_maxstep<0x114>(x);   // row_shr:4
    x = dpp_maxstep<0x118>(x);   // row_shr:8
    x = dpp_maxstep<0x142>(x);   // row_bcast15
    x = dpp_maxstep<0x143>(x);   // row_bcast31
    return __builtin_amdgcn_readlane(x, 63);
}

// exact 2^s as double for s in [-1022, 1023]
__device__ __forceinline__ double pow2d(int s) {
    return __longlong_as_double((long long)(1023 + s) << 52);
}

__global__ __launch_bounds__(TPB, 2) void dtw_kernel(
    const float2* __restrict__ snake,
    const float2* __restrict__ contour,
    float* __restrict__ out)
{
    const int t    = threadIdx.x;
    const int lane = t & 63;
    const int w    = t >> 6;                 // wave 0..7
    const int b    = blockIdx.x;             // batch
    const int il   = (w << 7) + 2 * lane;    // lo row
    const int ih   = il + 1;                 // hi row

    __shared__ double ringv[WPB][2][K];      // boundary ring (LDS only)
    __shared__ int    ringo[WPB][2];
    __shared__ float  initvals[3];           // R0[0], R1[0], R1[1]

    const float2* sg = snake   + (size_t)b * N;
    const float2* cg = contour + (size_t)b * N;
    const float2 sp_l = sg[il];              // snake points: registers
    const float2 sp_h = sg[ih];

    if (t < WPB * 2 * K) ((double*)ringv)[t] = 0.0;   // Z(INF) = 0
    if (t < WPB * 2)     ((int*)ringo)[t] = 0;
    if (t == 0) {
        // Diagonals 0 and 1 (reference `init`):
        float2 s0 = sg[0], s1 = sg[1], c0 = cg[0], c1 = cg[1];
        float d00 = sqdist2(s0, c0);
        initvals[0] = d00;
        initvals[1] = sqdist2(s0, c1) + d00;
        initvals[2] = sqdist2(s1, c0) + d00;
    }
    __syncthreads();

    // State entering d=2 (off = 0):
    //   cur_lo = Z_{d-1}[il], cur_hi = Z_{d-1}[ih], old_lo = Z_{d-2}[il],
    //   nbh1 = Z_{d-1}[il-1], nbh2 = Z_{d-2}[il-1]  (neighbor lane's hi row)
    double cur_lo = 0.0, cur_hi = 0.0, old_lo = 0.0;
    double nbh1 = 0.0, nbh2 = 0.0;
    int off = 0;
    bool adopted = (w == 0);
    if (t == 0) {            // rows 0,1: R1[0], R1[1], R0[0]
        cur_lo = (double)__builtin_amdgcn_exp2f(-L2E * initvals[1]);
        cur_hi = (double)__builtin_amdgcn_exp2f(-L2E * initvals[2]);
        old_lo = (double)__builtin_amdgcn_exp2f(-L2E * initvals[0]);
    } else if (t == 1) {     // row 2's left neighbor = row 1 at d=1
        nbh1 = (double)__builtin_amdgcn_exp2f(-L2E * initvals[2]);
    }

    double res = 1.0;                        // final-cell snapshot
    int res_off = 0;
    const bool snapw = (w == WPB - 1);       // only row 1023's value is read

    const int lo = (w == 0) ? 2 : (128 * w - 1);  // -1 pre-step seeds nbh1
    const int hi = 128 * w + 127 + (N - 1);       // 128w + 1150
    int d0 = 2 - K * w;

    double k2l[K], k2h[K];                   // step factors, f64 (cvt hoisted)
    double vr[K];                            // converted ring (lane 0 only;
                                             //  lanes>=1 stay exactly 0.0)
    #pragma unroll
    for (int k = 0; k < K; ++k) vr[k] = 0.0;

    // Epoch-0 factors. Contour reuse: c_h(k) = c_l(k-1).
    {
        float2 cprev = cg[(unsigned)(d0 - 1 - il) & (N - 1)];
        #pragma unroll
        for (int k = 0; k < K; ++k) {
            const unsigned ul = (unsigned)(d0 + k - il);
            const unsigned uh = (unsigned)(d0 + k - ih);
            float2 cc = cg[ul & (N - 1)];
            float el = __builtin_amdgcn_exp2f(sqdist2(sp_l, cc) * (-L2E));
            float eh = __builtin_amdgcn_exp2f(sqdist2(sp_h, cprev) * (-L2E));
            k2l[k] = (ul < (unsigned)N) ? (double)el : 0.0;
            k2h[k] = (uh < (unsigned)N) ? (double)eh : 0.0;
            cprev = cc;
        }
    }

    for (int g = 0; g < NGRP; ++g) {
        const bool overlap = (d0 <= hi) && (d0 + (K - 1) >= lo);
        if (overlap) {
            if (w > 0) {
                const int p = (g ^ 1) & 1;
                int oin = ringo[w - 1][p];            // LDS broadcast
                if (!adopted) { off = oin; adopted = true; }
                if (lane == 0) {
                    int dl = off - oin;
                    int c1 = min(max(dl, -1022), 1022);
                    int c2 = min(max(dl - c1, -1022), 1022);
                    double f1 = pow2d(c1), f2 = pow2d(c2);
                    const double* q = &ringv[w - 1][p][0];
                    #pragma unroll
                    for (int k = 0; k < K; ++k)
                        vr[k] = (q[k] * f1) * f2;
                }
                #pragma unroll
                for (int k = 0; k < K; ++k) PIN_D(vr[k]);
            }

            const int kres = (ih + N - 1) - d0;  // step of hi row's last cell
            const bool pub = (lane == 63) && (w < WPB - 1);

            // Chain: two INDEPENDENT cells per step (hi uses pre-update lo).
            // Neighbor pass: ONE wave_shr:1 DPP; nbh1 = up + vr[k] is exact
            // (lane 0: up==0.0 by bound-ctrl; lanes>=1: vr[k]==0.0 always).
            #pragma unroll
            for (int k = 0; k < K; ++k) {
                double zn_h = k2h[k] * ((old_lo + cur_lo) + cur_hi);
                double zn_l = k2l[k] * ((nbh2 + nbh1) + cur_lo);
                if (snapw && k == kres) { res = zn_h; res_off = off; }
                if (pub) ringv[w][g & 1][k] = zn_h;   // off-chain LDS store
                old_lo = cur_lo;
                cur_lo = zn_l;
                cur_hi = zn_h;
                double up = dpp_movd<0x138>(zn_h);    // wave_shr:1
                nbh2 = nbh1;
                nbh1 = up + vr[k];
            }

            if (pub) ringo[w][g & 1] = off;          // pre-rescale offset

            // Per-wave exact power-of-2 rescale (DPP max-reduce, no LDS).
            int el = (int)((__double_as_longlong(cur_lo) >> 52) & 0x7FF);
            int eh = (int)((__double_as_longlong(cur_hi) >> 52) & 0x7FF);
            int e = wave_max_i(max(el, eh));
            if (e > 0) {
                int sh = 1023 - e;
                int c1 = min(max(sh, -1022), 1022);
                int c2 = min(max(sh - c1, -1022), 1022);
                double f1 = pow2d(c1), f2 = pow2d(c2);
                cur_lo = (cur_lo * f1) * f2;
                cur_hi = (cur_hi * f1) * f2;
                old_lo = (old_lo * f1) * f2;
                nbh1   = (nbh1   * f1) * f2;
                nbh2   = (nbh2   * f1) * f2;
                off += sh;
            }
        }

        d0 += K;

        // Epoch bottom: next-epoch factors (cvt to f64 here, off-chain;
        // global loads may stay in flight across the lgkm-only barrier).
        {
            float2 cprev = cg[(unsigned)(d0 - 1 - il) & (N - 1)];
            #pragma unroll
            for (int k = 0; k < K; ++k) {
                const unsigned ul = (unsigned)(d0 + k - il);
                const unsigned uh = (unsigned)(d0 + k - ih);
                float2 cc = cg[ul & (N - 1)];
                float el2 = __builtin_amdgcn_exp2f(sqdist2(sp_l, cc) * (-L2E));
                float eh2 = __builtin_amdgcn_exp2f(sqdist2(sp_h, cprev) * (-L2E));
                k2l[k] = (ul < (unsigned)N) ? (double)el2 : 0.0;
                k2h[k] = (uh < (unsigned)N) ? (double)eh2 : 0.0;
                cprev = cc;
            }
        }
        #pragma unroll
        for (int k = 0; k < K; ++k) { PIN_D(k2l[k]); PIN_D(k2h[k]); }

        EPOCH_BARRIER();   // lgkmcnt(0) + s_barrier (no vmcnt drain)
    }

    // Row 1023 = hi row of wave 7, lane 63 (t = 511): res = Z of
    // R[1023,1023] at res_off (exact snapshot; rescales are powers of 2).
    if (t == TPB - 1) {
        double R = ((double)res_off - log2(res)) * LN2D;
        atomicAdd(out, (float)(R * (1.0 / 64.0)));
    }
}

extern "C" void kernel_launch(void* const* d_in, const int* in_sizes, int n_in,
                              void* d_out, int out_size, void* d_ws, size_t ws_size,
                              hipStream_t stream) {
    const float2* snake   = (const float2*)d_in[0];
    const float2* contour = (const float2*)d_in[1];
    float* out = (float*)d_out;
    // Harness re-poisons d_out to 0xAA before every timed launch.
    hipMemsetAsync(out, 0, sizeof(float), stream);
    dtw_kernel<<<64, TPB, 0, stream>>>(snake, contour, out);
}

// Round 25
// 336.610 us; speedup vs baseline: 1.0223x; 1.0223x over previous
//
#include <hip/hip_runtime.h>

// Soft-DTW (gamma=1), batched 64 x (1024 vs 1024, 2-D points).
//
// === FINAL (R22 champion, 287.4 us, absmax 0.0) ===
// Session: 534 -> 287.4 us (1.86x), bit-exact at every step.
// Key moves, in order of impact:
//  - exp2-domain recurrence: Z = 2^(off - R*log2e) turns softmin into
//    Z_d[i] = 2^(-D*log2e) * (Zdiag + Zup + Zleft) -- ZERO transcendentals
//    on the serial DP chain (R0-R7 arc; fp64 + per-wave offset covers the
//    ~400-bit within-wave dynamic range, R8).
//  - 2 rows/lane coarsening: hi cell's predecessors are the lane's own
//    registers; lo+hi independent per step (2x ILP); 8 waves/batch -> one
//    block per batch, 2 waves/SIMD (R15); slim f32 k2 arrays (R16).
//  - wave_shr:1 DPP (ctrl 0x138) single-op neighbor pass + dead final-cell
//    snapshot removed from waves 0-6 (R22: 315.9 -> 287.4).
// Closed axes (all measured losses/nulls): cross-block CU-spread
// (R10/11/13/14/18), K=8/32 (R8/R14/R20), producer-asm pins (R19),
// lgkm-only barrier (R23 null), chain micro-edits f64-k2/add-for-select
// (R24 regress), >2 waves/SIMD (structurally impossible).
// Residual gap to pure-issue floor (~208us) is f64 dep-chain latency +
// barrier convoy on a 2047-deep serial recurrence -- not reachable from
// HIP source without disasm-guided scheduling.
//
// Structure: one block per batch, 64 blocks x 512 thr, 8 waves (2/SIMD);
// lane owns rows 2l (lo) / 2l+1 (hi); contour reuse c_h(k) = c_l(k-1);
// LDS parity ring between waves (reader epoch g reads writer epoch g-1,
// parity (g^1)&1; overwrite 2 barriers later); K=16 diagonals/epoch, one
// __syncthreads per epoch.
//
// Core (verified absmax 0.0 since R8): per-cell op order
// zn = k2 * ((nb2 + nb1) + cur); f32->f64 widening of k2 exact; per-wave
// exact power-of-2 rescale per epoch (DPP max-reduce, pure VALU); lane-0
// neighbor values converted by exact 2^(off-oin) two-stage factors;
// inactive cells k2=0 -> zn=0. Final cell (row 1023, d=2046) snapshotted
// at its own step (exact); R = (res_off - log2(res)) * ln2; one atomicAdd
// per batch.

#define N 1024
#define TPB 512
#define WPB 8                                  // waves per block = per batch
#define K 16                                   // diagonals per epoch
#define NGRP ((128 * (WPB - 1) + 1148) / K + (WPB - 1) + 1)   // 135
#define L2E 1.442695040888963f
#define LN2D 0.6931471805599453

#define PIN_D(x) asm volatile("" :: "v"(x))
#define PIN_F(x) asm volatile("" :: "v"(x))

__device__ __forceinline__ float sqdist2(float2 a, float2 b) {
    float dx = a.x - b.x;
    float dy = a.y - b.y;
    return dx * dx + dy * dy;
}

// 64-bit DPP move (two 32-bit halves, same lane pattern; invalid lanes -> 0).
template <int CTRL>
__device__ __forceinline__ double dpp_movd(double src) {
    long long s = __double_as_longlong(src);
    int lo = __builtin_amdgcn_update_dpp(0, (int)(s & 0xffffffffLL),
                                         CTRL, 0xF, 0xF, false);
    int hi = __builtin_amdgcn_update_dpp(0, (int)(s >> 32),
                                         CTRL, 0xF, 0xF, false);
    return __longlong_as_double(((long long)hi << 32) | (unsigned int)lo);
}

template <int CTRL>
__device__ __forceinline__ int dpp_maxstep(int x) {
    int s = __builtin_amdgcn_update_dpp(0, x, CTRL, 0xF, 0xF, false);
    return max(x, s);
}

// Full 64-lane max of a nonneg int, pure VALU (no LDS); result wave-uniform.
__device__ __forceinline__ int wave_max_i(int x) {
    x = dpp_maxstep<0x111>(x);   // row_shr:1
    x = dpp_maxstep<0x112>(x);   // row_shr:2
    x = dpp_maxstep<0x114>(x);   // row_shr:4
    x = dpp_maxstep<0x118>(x);   // row_shr:8
    x = dpp_maxstep<0x142>(x);   // row_bcast15
    x = dpp_maxstep<0x143>(x);   // row_bcast31
    return __builtin_amdgcn_readlane(x, 63);
}

// exact 2^s as double for s in [-1022, 1023]
__device__ __forceinline__ double pow2d(int s) {
    return __longlong_as_double((long long)(1023 + s) << 52);
}

__global__ __launch_bounds__(TPB, 2) void dtw_kernel(
    const float2* __restrict__ snake,
    const float2* __restrict__ contour,
    float* __restrict__ out)
{
    const int t    = threadIdx.x;
    const int lane = t & 63;
    const int w    = t >> 6;                 // wave 0..7
    const int b    = blockIdx.x;             // batch
    const int il   = (w << 7) + 2 * lane;    // lo row
    const int ih   = il + 1;                 // hi row

    __shared__ double ringv[WPB][2][K];      // boundary ring (LDS only)
    __shared__ int    ringo[WPB][2];
    __shared__ float  initvals[3];           // R0[0], R1[0], R1[1]

    const float2* sg = snake   + (size_t)b * N;
    const float2* cg = contour + (size_t)b * N;
    const float2 sp_l = sg[il];              // snake points: registers
    const float2 sp_h = sg[ih];

    if (t < WPB * 2 * K) ((double*)ringv)[t] = 0.0;   // Z(INF) = 0
    if (t < WPB * 2)     ((int*)ringo)[t] = 0;
    if (t == 0) {
        // Diagonals 0 and 1 (reference `init`):
        float2 s0 = sg[0], s1 = sg[1], c0 = cg[0], c1 = cg[1];
        float d00 = sqdist2(s0, c0);
        initvals[0] = d00;
        initvals[1] = sqdist2(s0, c1) + d00;
        initvals[2] = sqdist2(s1, c0) + d00;
    }
    __syncthreads();

    // State entering d=2 (off = 0):
    //   cur_lo = Z_{d-1}[il], cur_hi = Z_{d-1}[ih], old_lo = Z_{d-2}[il],
    //   nbh1 = Z_{d-1}[il-1], nbh2 = Z_{d-2}[il-1]  (neighbor lane's hi row)
    double cur_lo = 0.0, cur_hi = 0.0, old_lo = 0.0;
    double nbh1 = 0.0, nbh2 = 0.0;
    int off = 0;
    bool adopted = (w == 0);
    if (t == 0) {            // rows 0,1: R1[0], R1[1], R0[0]
        cur_lo = (double)__builtin_amdgcn_exp2f(-L2E * initvals[1]);
        cur_hi = (double)__builtin_amdgcn_exp2f(-L2E * initvals[2]);
        old_lo = (double)__builtin_amdgcn_exp2f(-L2E * initvals[0]);
    } else if (t == 1) {     // row 2's left neighbor = row 1 at d=1
        nbh1 = (double)__builtin_amdgcn_exp2f(-L2E * initvals[2]);
    }

    double res = 1.0;                        // final-cell snapshot
    int res_off = 0;
    const bool snapw = (w == WPB - 1);       // only row 1023's value is read

    const int lo = (w == 0) ? 2 : (128 * w - 1);  // -1 pre-step seeds nbh1
    const int hi = 128 * w + 127 + (N - 1);       // 128w + 1150
    int d0 = 2 - K * w;

    float k2l[K], k2h[K];                    // step factors, f32
    double vr[K];                            // converted ring (lane 0 only)
    #pragma unroll
    for (int k = 0; k < K; ++k) vr[k] = 0.0;

    // Epoch-0 factors. Contour reuse: c_h(k) = c_l(k-1).
    {
        float2 cprev = cg[(unsigned)(d0 - 1 - il) & (N - 1)];
        #pragma unroll
        for (int k = 0; k < K; ++k) {
            const unsigned ul = (unsigned)(d0 + k - il);
            const unsigned uh = (unsigned)(d0 + k - ih);
            float2 cc = cg[ul & (N - 1)];
            float el = __builtin_amdgcn_exp2f(sqdist2(sp_l, cc) * (-L2E));
            float eh = __builtin_amdgcn_exp2f(sqdist2(sp_h, cprev) * (-L2E));
            k2l[k] = (ul < (unsigned)N) ? el : 0.0f;
            k2h[k] = (uh < (unsigned)N) ? eh : 0.0f;
            cprev = cc;
        }
    }

    for (int g = 0; g < NGRP; ++g) {
        const bool overlap = (d0 <= hi) && (d0 + (K - 1) >= lo);
        if (overlap) {
            if (w > 0) {
                const int p = (g ^ 1) & 1;
                int oin = ringo[w - 1][p];            // LDS broadcast
                if (!adopted) { off = oin; adopted = true; }
                if (lane == 0) {
                    int dl = off - oin;
                    int c1 = min(max(dl, -1022), 1022);
                    int c2 = min(max(dl - c1, -1022), 1022);
                    double f1 = pow2d(c1), f2 = pow2d(c2);
                    const double* q = &ringv[w - 1][p][0];
                    #pragma unroll
                    for (int k = 0; k < K; ++k)
                        vr[k] = (q[k] * f1) * f2;
                }
                #pragma unroll
                for (int k = 0; k < K; ++k) PIN_D(vr[k]);
            }

            const int kres = (ih + N - 1) - d0;  // step of hi row's last cell
            const bool pub = (lane == 63) && (w < WPB - 1);

            // Chain: two INDEPENDENT cells per step (hi uses pre-update lo).
            // Neighbor pass: ONE wave_shr:1 DPP (lane l <- lane l-1; lane 0
            // bound-ctrl 0, then selected to vr[k]).
            #pragma unroll
            for (int k = 0; k < K; ++k) {
                double zn_h = (double)k2h[k] * ((old_lo + cur_lo) + cur_hi);
                double zn_l = (double)k2l[k] * ((nbh2 + nbh1) + cur_lo);
                if (snapw && k == kres) { res = zn_h; res_off = off; }
                if (pub) ringv[w][g & 1][k] = zn_h;   // off-chain LDS store
                old_lo = cur_lo;
                cur_lo = zn_l;
                cur_hi = zn_h;
                double up = dpp_movd<0x138>(zn_h);    // wave_shr:1
                nbh2 = nbh1;
                nbh1 = (lane == 0) ? vr[k] : up;
            }

            if (pub) ringo[w][g & 1] = off;          // pre-rescale offset

            // Per-wave exact power-of-2 rescale (DPP max-reduce, no LDS).
            int el = (int)((__double_as_longlong(cur_lo) >> 52) & 0x7FF);
            int eh = (int)((__double_as_longlong(cur_hi) >> 52) & 0x7FF);
            int e = wave_max_i(max(el, eh));
            if (e > 0) {
                int sh = 1023 - e;
                int c1 = min(max(sh, -1022), 1022);
                int c2 = min(max(sh - c1, -1022), 1022);
                double f1 = pow2d(c1), f2 = pow2d(c2);
                cur_lo = (cur_lo * f1) * f2;
                cur_hi = (cur_hi * f1) * f2;
                old_lo = (old_lo * f1) * f2;
                nbh1   = (nbh1   * f1) * f2;
                nbh2   = (nbh2   * f1) * f2;
                off += sh;
            }
        }

        d0 += K;

        // Epoch bottom: next-epoch factors.
        {
            float2 cprev = cg[(unsigned)(d0 - 1 - il) & (N - 1)];
            #pragma unroll
            for (int k = 0; k < K; ++k) {
                const unsigned ul = (unsigned)(d0 + k - il);
                const unsigned uh = (unsigned)(d0 + k - ih);
                float2 cc = cg[ul & (N - 1)];
                float el2 = __builtin_amdgcn_exp2f(sqdist2(sp_l, cc) * (-L2E));
                float eh2 = __builtin_amdgcn_exp2f(sqdist2(sp_h, cprev) * (-L2E));
                k2l[k] = (ul < (unsigned)N) ? el2 : 0.0f;
                k2h[k] = (uh < (unsigned)N) ? eh2 : 0.0f;
                cprev = cc;
            }
        }
        #pragma unroll
        for (int k = 0; k < K; ++k) { PIN_F(k2l[k]); PIN_F(k2h[k]); }

        __syncthreads();
    }

    // Row 1023 = hi row of wave 7, lane 63 (t = 511): res = Z of
    // R[1023,1023] at res_off (exact snapshot; rescales are powers of 2).
    if (t == TPB - 1) {
        double R = ((double)res_off - log2(res)) * LN2D;
        atomicAdd(out, (float)(R * (1.0 / 64.0)));
    }
}

extern "C" void kernel_launch(void* const* d_in, const int* in_sizes, int n_in,
                              void* d_out, int out_size, void* d_ws, size_t ws_size,
                              hipStream_t stream) {
    const float2* snake   = (const float2*)d_in[0];
    const float2* contour = (const float2*)d_in[1];
    float* out = (float*)d_out;
    // Harness re-poisons d_out to 0xAA before every timed launch.
    hipMemsetAsync(out, 0, sizeof(float), stream);
    dtw_kernel<<<64, TPB, 0, stream>>>(snake, contour, out);
}